// Round 13
// baseline (603.932 us; speedup 1.0000x reference)
//
#include <hip/hip_runtime.h>

#define NB 1024
#define NT 256
#define IND 10
#define HID 64

// Packed weight array Wp (float offsets), all [k][64j] lane-coalesced:
//   OFF_WA [120][64]: W1[11+q]+W1[132+q]   (q = qmap(k))
//   OFF_WB [120][64]: W1[253+q]            (gated by rel0)
//   OFF_WC [120][64]: W1[374+q]            (gated by rel1)
//   OFF_WD [16][64] : rel2-gated 17-term weights (sig2f[1..16] part)
//   OFF_WX [28][64] : 0-9 wrel, 10-19 wf, 20-23 tt coefs (ws,wb,wc,wd),
//                     24 w_one, 25 b1, 26-27 pad
#define OFF_WA 0
#define OFF_WB 7680
#define OFF_WC 15360
#define OFF_WD 23040
#define OFF_WX 24064
#define WP_FLOATS 25856

__device__ __forceinline__ int qmap(int kk) {
    if (kk < 10) return 1 + kk;
    if (kk < 20) return 11 * (kk - 10 + 1);
    int i = (kk - 20) / 10, c = (kk - 20) % 10;
    return 11 * (i + 1) + 1 + c;
}

__global__ void pack_kernel(const float* __restrict__ W1, const float* __restrict__ b1,
                            float* __restrict__ Wp) {
    int idx = blockIdx.x * 256 + threadIdx.x;
    if (idx >= WP_FLOATS) return;
    float v = 0.f;
    if (idx < OFF_WB) {
        int k = idx >> 6, j = idx & 63; int q = qmap(k);
        v = W1[(11 + q) * 64 + j] + W1[(132 + q) * 64 + j];
    } else if (idx < OFF_WC) {
        int e = idx - OFF_WB; int k = e >> 6, j = e & 63;
        v = W1[(253 + qmap(k)) * 64 + j];
    } else if (idx < OFF_WD) {
        int e = idx - OFF_WC; int k = e >> 6, j = e & 63;
        v = W1[(374 + qmap(k)) * 64 + j];
    } else if (idx < OFF_WX) {
        int e = idx - OFF_WD; int i = e >> 6, j = e & 63;
        if (i < 10)       v = W1[(496 + i) * 64 + j];
        else if (i == 10) v = W1[506 * 64 + j];
        else if (i < 16)  v = W1[(507 + (i - 11)) * 64 + j];
    } else {
        int e = idx - OFF_WX; int o = e >> 6, j = e & 63;
        if (o < 10)       v = W1[(1 + o) * 64 + j];
        else if (o < 20)  v = W1[(512 + o - 10) * 64 + j];
        else if (o == 20) v = W1[11 * 64 + j] + W1[132 * 64 + j];
        else if (o == 21) v = W1[253 * 64 + j];
        else if (o == 22) v = W1[374 * 64 + j];
        else if (o == 23) v = W1[495 * 64 + j];
        else if (o == 24) v = W1[0 * 64 + j];
        else if (o == 25) v = b1[j];
    }
    Wp[idx] = v;
}

__device__ __forceinline__ unsigned bf16rne(float x) {
    unsigned u = __float_as_uint(x);
    return (u + 0x7fffu + ((u >> 16) & 1u)) >> 16;
}

// ---------------------------------------------------------------------------
// presig v8 = presig7 with bf16 LDS staging (error budget: absmax 0.25 vs
// threshold 3.7):
//  - sP stored as bf16 [t][136 halves]: j-phase P loads are 4 ds_read_b128
//    per t per wave (was 8) — the LDS pipe (1/CU, shared by 4 SIMDs) was the
//    ~2:1 oversubscribed bottleneck.  Unpack = 2 VALU/dword on idle VALU.
//  - sAcc stored as bf16 (16 KB): finalize = one ds_read_b64.
//  - LDS 77.3 -> 44.5 KB -> 3 blocks/CU (occupancy 21 -> ~31%).
// Scan phase and barrier structure unchanged from presig7 (proven).
// ---------------------------------------------------------------------------
__global__ __launch_bounds__(256, 1) void presig8_kernel(
    const float* __restrict__ features, const float* __restrict__ Wp,
    float* __restrict__ pre1) {
    const int b = blockIdx.x;
    const int tid = threadIdx.x;
    const int l = tid & 63;
    const int wu = tid >> 6;

    __shared__ __align__(16) float sF[NT * IND];              // 10240 B
    __shared__ __align__(16) unsigned short sPh[64 * 136];    // 17408 B
    __shared__ __align__(16) unsigned short sAccH[2][16 * 4 * 64]; // 16384 B
    __shared__ float sBase[128];                              // 512 B

    {
        const float4* src = (const float4*)(features + b * (NT * IND));
        float4* dst = (float4*)sF;
        for (int e = tid; e < NT * IND / 4; e += 256) dst[e] = src[e];
    }
    float f0[IND];
#pragma unroll
    for (int c = 0; c < IND; ++c) f0[c] = features[b * (NT * IND) + c];

    float wxv[26];
#pragma unroll
    for (int o = 0; o < 26; ++o) wxv[o] = Wp[OFF_WX + o * 64 + l];

    if (tid < 128) sBase[tid] = 0.f;
    __syncthreads();   // B0: sF + sBase ready

    for (int tile = 0; tile < 4; ++tile) {
        const int t0 = tile * 64;

        // ---- scan phase (identical math to presig7) ----
        const int r = t0 + l;
        float rf = (float)r;
        float fr[IND], rel[IND], inc[IND];
#pragma unroll
        for (int c = 0; c < IND; ++c) fr[c] = sF[r * IND + c];
#pragma unroll
        for (int c = 0; c < IND; ++c) rel[c] = fr[c] - f0[c];
        {
            bool last = (r >= NT - 1);
#pragma unroll
            for (int c = 0; c < IND; ++c)
                inc[c] = last ? 0.f : (sF[(r + 1) * IND + c] - fr[c]);
        }
        float p[30], own[30];
        if (wu == 0) {
#pragma unroll
            for (int c = 0; c < 10; ++c) p[c] = rf * inc[c];
#pragma unroll
            for (int i = 0; i < 10; ++i) p[10 + i] = rel[i];
#pragma unroll
            for (int c = 0; c < 10; ++c) p[20 + c] = rel[0] * inc[c];
        } else {
            const int i0 = 3 * wu - 2;
#pragma unroll
            for (int q = 0; q < 30; ++q) {
                int i = i0 + q / 10, c = q % 10;
                p[q] = rel[i] * inc[c];
            }
        }
#pragma unroll
        for (int i = 0; i < 30; ++i) own[i] = p[i];
#pragma unroll
        for (int dsh = 0; dsh < 6; ++dsh) {
            const int d = 1 << dsh;
            bool ok = (l >= d);
#pragma unroll
            for (int i = 0; i < 30; ++i) {
                float v = __shfl_up(p[i], d, 64);
                if (ok) p[i] += v;
            }
        }
        float inv_r = (r > 0) ? 1.f / rf : 0.f;
        {
            float v[30];
#pragma unroll
            for (int i = 0; i < 30; ++i) {
                float x = sBase[wu * 32 + i] + p[i] - own[i];
                if (wu == 0 && i < 20) x *= inv_r;
                v[i] = x;
            }
            // bf16-pack into sPh[l][32*wu .. +32) (halves 30,31 zero pad)
            unsigned* row = (unsigned*)&sPh[l * 136 + 32 * wu];
#pragma unroll
            for (int i2 = 0; i2 < 15; ++i2)
                row[i2] = bf16rne(v[2 * i2]) | (bf16rne(v[2 * i2 + 1]) << 16);
            row[15] = 0u;
        }
        if (l == 63) {   // wave-exclusive slice; in-wave order suffices
#pragma unroll
            for (int i = 0; i < 30; ++i) sBase[wu * 32 + i] += p[i];
        }
        // no Bb barrier: sPh/sBase are intra-wave (lgkmcnt orders write->read)

        // ---- per-tile weight regs; asm pin blocks LICM hoist into scan ----
        int kbase = 30 * wu;
        asm volatile("" : "+v"(kbase));
        float wav[30], wbv[30], wcv[30];
#pragma unroll
        for (int i = 0; i < 30; ++i) {
            int k = kbase + i;
            wav[i] = Wp[OFF_WA + (k << 6) + l];
            wbv[i] = Wp[OFF_WB + (k << 6) + l];
            wcv[i] = Wp[OFF_WC + (k << 6) + l];
        }
        float wdv[16];
#pragma unroll
        for (int i = 0; i < 16; ++i) wdv[i] = Wp[OFF_WD + (i << 6) + l];

        // ---- j-phase: 4 quarters of 16 t's, double-buffered bf16 sAcc ----
#pragma unroll 1
        for (int tq = 0; tq < 4; ++tq) {
            unsigned short* bufh = sAccH[tq & 1];
#pragma unroll 1
            for (int u = 0; u < 16; ++u) {
                int t = tq * 16 + u;
                const uint4* Pp = (const uint4*)&sPh[t * 136 + 32 * wu];
                uint4 d0 = Pp[0], d1 = Pp[1], d2 = Pp[2], d3 = Pp[3];
#define ULO(w) __uint_as_float((w) << 16)
#define UHI(w) __uint_as_float((w) & 0xffff0000u)
                float p0 = ULO(d0.x), p1 = UHI(d0.x), p2 = ULO(d0.y), p3 = UHI(d0.y);
                float p4 = ULO(d0.z), p5 = UHI(d0.z), p6 = ULO(d0.w), p7 = UHI(d0.w);
                float p8 = ULO(d1.x), p9 = UHI(d1.x), p10 = ULO(d1.y), p11 = UHI(d1.y);
                float p12 = ULO(d1.z), p13 = UHI(d1.z), p14 = ULO(d1.w), p15 = UHI(d1.w);
                float p16 = ULO(d2.x), p17 = UHI(d2.x), p18 = ULO(d2.y), p19 = UHI(d2.y);
                float p20 = ULO(d2.z), p21 = UHI(d2.z), p22 = ULO(d2.w), p23 = UHI(d2.w);
                float p24 = ULO(d3.x), p25 = UHI(d3.x), p26 = ULO(d3.y), p27 = UHI(d3.y);
                float p28 = ULO(d3.z), p29 = UHI(d3.z);
#undef ULO
#undef UHI
                float rr0 = sF[(t0 + t) * IND + 0] - f0[0];
                float rr1 = sF[(t0 + t) * IND + 1] - f0[1];
                float rr2 = sF[(t0 + t) * IND + 2] - f0[2];
                float a = 0.f, bb = 0.f, cv = 0.f;
#define FMA1(P_, I_) a = fmaf(P_, wav[I_], a); bb = fmaf(P_, wbv[I_], bb); \
                     cv = fmaf(P_, wcv[I_], cv);
                FMA1(p0, 0) FMA1(p1, 1) FMA1(p2, 2) FMA1(p3, 3) FMA1(p4, 4)
                FMA1(p5, 5) FMA1(p6, 6) FMA1(p7, 7) FMA1(p8, 8) FMA1(p9, 9)
                FMA1(p10, 10) FMA1(p11, 11) FMA1(p12, 12) FMA1(p13, 13) FMA1(p14, 14)
                FMA1(p15, 15) FMA1(p16, 16) FMA1(p17, 17) FMA1(p18, 18) FMA1(p19, 19)
                FMA1(p20, 20) FMA1(p21, 21) FMA1(p22, 22) FMA1(p23, 23) FMA1(p24, 24)
                FMA1(p25, 25) FMA1(p26, 26) FMA1(p27, 27) FMA1(p28, 28) FMA1(p29, 29)
#undef FMA1
                float val = a + rr0 * bb + rr1 * cv;
                if (wu == 0) {
                    float dd = 0.f;
                    dd = fmaf(p0, wdv[0], dd); dd = fmaf(p1, wdv[1], dd);
                    dd = fmaf(p2, wdv[2], dd); dd = fmaf(p3, wdv[3], dd);
                    dd = fmaf(p4, wdv[4], dd); dd = fmaf(p5, wdv[5], dd);
                    dd = fmaf(p6, wdv[6], dd); dd = fmaf(p7, wdv[7], dd);
                    dd = fmaf(p8, wdv[8], dd); dd = fmaf(p9, wdv[9], dd);
                    dd = fmaf(p10, wdv[10], dd);
                    dd = fmaf(p20, wdv[11], dd); dd = fmaf(p21, wdv[12], dd);
                    dd = fmaf(p22, wdv[13], dd); dd = fmaf(p23, wdv[14], dd);
                    dd = fmaf(p24, wdv[15], dd);
                    val = fmaf(rr2, dd, val);
                }
                bufh[(u * 64 + l) * 4 + wu] = (unsigned short)bf16rne(val);
            }
            __syncthreads();   // Bq1: bufh ready (cross-wave)
#pragma unroll 1
            for (int u = 0; u < 4; ++u) {
                int uu = wu * 4 + u;
                int t = tq * 16 + uu;
                int rr = t0 + t;
                float rf2 = (float)rr;
                float inv2 = (rr > 0) ? 1.f / rf2 : 0.f;
                float ttv = 0.5f * (rf2 - 1.f) * inv2;
                float gate = (rr > 0) ? 1.f : 0.f;
                uint2 hw = *(const uint2*)&bufh[(uu * 64 + l) * 4];
                float s0 = __uint_as_float(hw.x << 16);
                float s1 = __uint_as_float(hw.x & 0xffff0000u);
                float s2 = __uint_as_float(hw.y << 16);
                float s3 = __uint_as_float(hw.y & 0xffff0000u);
                float pre = (s0 + s1) + (s2 + s3);
                float acc2 = wxv[25];
                float rr0 = 0.f, rr1 = 0.f, rr2 = 0.f;
#pragma unroll
                for (int c = 0; c < 10; ++c) {
                    float Fv = sF[rr * IND + c];
                    float rv = Fv - f0[c];
                    if (c == 0) rr0 = rv; else if (c == 1) rr1 = rv; else if (c == 2) rr2 = rv;
                    acc2 = fmaf(rv, wxv[c], acc2);
                    acc2 = fmaf(Fv, wxv[10 + c], acc2);
                }
                float ttc = wxv[20] + rr0 * wxv[21] + rr1 * wxv[22] + rr2 * wxv[23];
                pre += acc2 + ttv * ttc + gate * wxv[24];
                pre1[b * (NT * HID) + rr * HID + l] = pre;
            }
            // no Bq2: double buffer; reuse separated by Bq1(next)/Bq1(next tile)
        }
    }
}

// ---------------------------------------------------------------------------
// scan (r9/r12-proven, ~120 us): 1 wave per batch, grid 1024.  LDS-b128
// broadcast GEMV, NO barriers (single-wave lgkmcnt ordering), DPP reduce,
// 8-deep global prefetch ring.
// ---------------------------------------------------------------------------
template <int CTRL, int RMASK>
__device__ __forceinline__ float dpp_add(float x) {
    int v = __builtin_amdgcn_update_dpp(0, __float_as_int(x), CTRL, RMASK, 0xf, false);
    return x + __int_as_float(v);
}

#define W2_EACH(X) X(0) X(1) X(2) X(3) X(4) X(5) X(6) X(7) \
    X(8) X(9) X(10) X(11) X(12) X(13) X(14) X(15)

__global__ __launch_bounds__(64, 1) void scan_kernel(
    const float* __restrict__ pre1, const float* __restrict__ W1,
    const float* __restrict__ W2, const float* __restrict__ b2,
    const float* __restrict__ W3, const float* __restrict__ b3,
    float* __restrict__ out) {
    const int b = blockIdx.x;
    const int j = threadIdx.x;

    __shared__ __align__(16) float sH[64];

#define DECLW(q) float4 w2_##q = make_float4( \
        W2[(4*(q)+0)*64 + j], W2[(4*(q)+1)*64 + j], \
        W2[(4*(q)+2)*64 + j], W2[(4*(q)+3)*64 + j]);
    W2_EACH(DECLW)
#undef DECLW
    float w1l = W1[522 * 64 + j];
    float b2j = b2[j], w3j = W3[j], b3v = b3[0];

    const float* pb_ = pre1 + b * (NT * HID);
    float delta = 0.f;
    float outbuf = 0.f;

#define GEMVQ(q) { float4 h4 = *(const float4*)&sH[4*(q)]; \
        a0 = fmaf(h4.x, w2_##q.x, a0); a1 = fmaf(h4.y, w2_##q.y, a1); \
        a2 = fmaf(h4.z, w2_##q.z, a2); a3 = fmaf(h4.w, w2_##q.w, a3); }

#define SCAN_STEP(pv, mm) { \
        float h1 = fmaxf(fmaf(delta, w1l, (pv)), 0.f); \
        sH[j] = h1; \
        float a0 = 0.f, a1 = 0.f, a2 = 0.f, a3 = 0.f; \
        W2_EACH(GEMVQ) \
        float h2 = fmaxf((a0 + a1) + (a2 + a3) + b2j, 0.f); \
        float qv = h2 * w3j; \
        qv = dpp_add<0x111, 0xf>(qv); \
        qv = dpp_add<0x112, 0xf>(qv); \
        qv = dpp_add<0x114, 0xf>(qv); \
        qv = dpp_add<0x118, 0xf>(qv); \
        qv = dpp_add<0x142, 0xa>(qv); \
        qv = dpp_add<0x143, 0xc>(qv); \
        float tot = __uint_as_float(__builtin_amdgcn_readlane(__float_as_uint(qv), 63)); \
        delta = tot + b3v; \
        if (j == ((mm) & 63)) outbuf = delta; \
        if (((mm) & 63) == 63) out[b * NT + ((mm) & ~63) + j] = outbuf; }

    float r0 = pb_[0 * 64 + j], r1 = pb_[1 * 64 + j], r2 = pb_[2 * 64 + j],
          r3 = pb_[3 * 64 + j], r4 = pb_[4 * 64 + j], r5 = pb_[5 * 64 + j],
          r6 = pb_[6 * 64 + j], r7 = pb_[7 * 64 + j];
    for (int g = 0; g < NT; g += 8) {
        int nb = g + 8;
        float n0 = pb_[min(nb + 0, NT - 1) * 64 + j];
        float n1 = pb_[min(nb + 1, NT - 1) * 64 + j];
        float n2 = pb_[min(nb + 2, NT - 1) * 64 + j];
        float n3 = pb_[min(nb + 3, NT - 1) * 64 + j];
        float n4 = pb_[min(nb + 4, NT - 1) * 64 + j];
        float n5 = pb_[min(nb + 5, NT - 1) * 64 + j];
        float n6 = pb_[min(nb + 6, NT - 1) * 64 + j];
        float n7 = pb_[min(nb + 7, NT - 1) * 64 + j];
        SCAN_STEP(r0, g + 0)
        SCAN_STEP(r1, g + 1)
        SCAN_STEP(r2, g + 2)
        SCAN_STEP(r3, g + 3)
        SCAN_STEP(r4, g + 4)
        SCAN_STEP(r5, g + 5)
        SCAN_STEP(r6, g + 6)
        SCAN_STEP(r7, g + 7)
        r0 = n0; r1 = n1; r2 = n2; r3 = n3; r4 = n4; r5 = n5; r6 = n6; r7 = n7;
    }
#undef SCAN_STEP
#undef GEMVQ
}

// ---------------------------------------------------------------------------
// Fallback (round-1 fused kernel) if workspace is too small.
// ---------------------------------------------------------------------------
__global__ __launch_bounds__(256) void logsig_hedge_fallback(
    const float* __restrict__ features, const float* __restrict__ W1,
    const float* __restrict__ b1, const float* __restrict__ W2,
    const float* __restrict__ b2, const float* __restrict__ W3,
    const float* __restrict__ b3, float* __restrict__ out) {
    const int b = blockIdx.x;
    const int tid = threadIdx.x;
    const int j = tid & 63;
    const int s = tid >> 6;

    __shared__ __align__(16) float sF[NT * IND];
    __shared__ __align__(16) float sSig[128];
    __shared__ float sA[IND], sB[IND], sC[IND * IND];
    __shared__ float sRel[IND];
    __shared__ __align__(16) float sPart[4 * 64];
    __shared__ __align__(16) float sH1[64];

    for (int idx = tid; idx < NT * IND; idx += 256)
        sF[idx] = features[b * (NT * IND) + idx];
    if (tid < 100) sC[tid] = 0.f;
    else if (tid < 110) sA[tid - 100] = 0.f;
    else if (tid < 120) sB[tid - 110] = 0.f;
    else if (tid >= 121 && tid < 128) sSig[tid] = 0.f;

    float vs[32], vb[32], vc[32];
#pragma unroll
    for (int mm = 0; mm < 32; ++mm) {
        int mp = 32 * s + mm;
        if (mp < 121) {
            vs[mm] = W1[(11 + mp) * 64 + j] + W1[(132 + mp) * 64 + j];
            vb[mm] = W1[(253 + mp) * 64 + j];
            vc[mm] = W1[(374 + mp) * 64 + j];
        } else { vs[mm] = 0.f; vb[mm] = 0.f; vc[mm] = 0.f; }
    }
    float ex[17];
#pragma unroll
    for (int q = 0; q < 17; ++q) ex[q] = 0.f;
    if (s == 1) {
#pragma unroll
        for (int q = 0; q < 11; ++q) ex[q] = W1[q * 64 + j];
    } else if (s == 2) {
#pragma unroll
        for (int q = 0; q < 10; ++q) ex[q] = W1[(512 + q) * 64 + j];
        ex[10] = b1[j];
    } else if (s == 3) {
#pragma unroll
        for (int q = 0; q < 17; ++q) ex[q] = W1[(495 + q) * 64 + j];
    }
    float w2p[16];
#pragma unroll
    for (int ii = 0; ii < 16; ++ii) w2p[ii] = W2[(16 * s + ii) * 64 + j];

    float w1l = 0.f, b2j = 0.f, w3j = 0.f, b3v = 0.f;
    if (s == 0) { w1l = W1[522 * 64 + j]; b2j = b2[j]; w3j = W3[j]; b3v = b3[0]; }
    float delta = 0.f;

    __syncthreads();

    for (int m = 0; m < NT; ++m) {
        if (m > 0) {
            if (tid < 100) {
                int i = tid / 10, c = tid % 10;
                float rp = sF[(m - 1) * 10 + i] - sF[i];
                float ic = sF[m * 10 + c] - sF[(m - 1) * 10 + c];
                sC[tid] += rp * ic;
            } else if (tid < 110) {
                int i = tid - 100;
                sA[i] += (float)(m - 1) * (sF[m * 10 + i] - sF[(m - 1) * 10 + i]);
            } else if (tid < 120) {
                int i = tid - 110;
                sB[i] += sF[(m - 1) * 10 + i] - sF[i];
            }
            __syncthreads();
            float inv_k = 1.0f / (float)m;
            if (tid == 0) sSig[0] = 0.5f * (float)(m - 1) * inv_k;
            else if (tid < 11) sSig[tid] = inv_k * sA[tid - 1];
            else if (tid < 121) {
                int i = tid / 11 - 1, c = tid % 11;
                sSig[tid] = (c == 0) ? inv_k * sB[i] : sC[i * 10 + (c - 1)];
            } else if (tid < 131) {
                int f = tid - 121;
                sRel[f] = sF[m * 10 + f] - sF[f];
            }
            __syncthreads();
        }
        float part = 0.f;
        if (m > 0) {
            float pa = 0.f, pb = 0.f, pc = 0.f;
#pragma unroll
            for (int q = 0; q < 8; ++q) {
                float4 sv = *(const float4*)&sSig[32 * s + 4 * q];
                pa = fmaf(sv.x, vs[4 * q + 0], pa);
                pb = fmaf(sv.x, vb[4 * q + 0], pb);
                pc = fmaf(sv.x, vc[4 * q + 0], pc);
                pa = fmaf(sv.y, vs[4 * q + 1], pa);
                pb = fmaf(sv.y, vb[4 * q + 1], pb);
                pc = fmaf(sv.y, vc[4 * q + 1], pc);
                pa = fmaf(sv.z, vs[4 * q + 2], pa);
                pb = fmaf(sv.z, vb[4 * q + 2], pb);
                pc = fmaf(sv.z, vc[4 * q + 2], pc);
                pa = fmaf(sv.w, vs[4 * q + 3], pa);
                pb = fmaf(sv.w, vb[4 * q + 3], pb);
                pc = fmaf(sv.w, vc[4 * q + 3], pc);
            }
            part = pa + sRel[0] * pb + sRel[1] * pc;
            if (s == 3) {
                float pd = 0.f;
#pragma unroll
                for (int q = 0; q < 17; ++q) pd = fmaf(sSig[q], ex[q], pd);
                part = fmaf(sRel[2], pd, part);
            }
            if (s == 1) {
                part += ex[0];
#pragma unroll
                for (int i = 0; i < 10; ++i) part = fmaf(sRel[i], ex[1 + i], part);
            }
        }
        if (s == 2) {
            float pf = ex[10];
#pragma unroll
            for (int f = 0; f < 10; ++f) pf = fmaf(sF[m * 10 + f], ex[f], pf);
            part += pf;
        }
        sPart[s * 64 + j] = part;
        __syncthreads();
        if (s == 0) {
            float x = sPart[j] + sPart[64 + j] + sPart[128 + j] + sPart[192 + j];
            sH1[j] = fmaxf(fmaf(delta, w1l, x), 0.f);
        }
        __syncthreads();
        {
            float hp = 0.f;
#pragma unroll
            for (int q = 0; q < 4; ++q) {
                float4 hv = *(const float4*)&sH1[16 * s + 4 * q];
                hp = fmaf(hv.x, w2p[4 * q + 0], hp);
                hp = fmaf(hv.y, w2p[4 * q + 1], hp);
                hp = fmaf(hv.z, w2p[4 * q + 2], hp);
                hp = fmaf(hv.w, w2p[4 * q + 3], hp);
            }
            sPart[s * 64 + j] = hp;
        }
        __syncthreads();
        if (s == 0) {
            float x2 = sPart[j] + sPart[64 + j] + sPart[128 + j] + sPart[192 + j] + b2j;
            float h2 = fmaxf(x2, 0.f);
            float dv = h2 * w3j;
#pragma unroll
            for (int off = 32; off > 0; off >>= 1) dv += __shfl_xor(dv, off, 64);
            delta = dv + b3v;
            if (j == 0) out[b * NT + m] = delta;
        }
        __syncthreads();
    }
}

extern "C" void kernel_launch(void* const* d_in, const int* in_sizes, int n_in,
                              void* d_out, int out_size, void* d_ws, size_t ws_size,
                              hipStream_t stream) {
    const float* features = (const float*)d_in[0];
    const float* W1 = (const float*)d_in[1];
    const float* b1 = (const float*)d_in[2];
    const float* W2 = (const float*)d_in[3];
    const float* b2 = (const float*)d_in[4];
    const float* W3 = (const float*)d_in[5];
    const float* b3 = (const float*)d_in[6];
    float* out = (float*)d_out;

    const size_t w_pad     = (((size_t)WP_FLOATS * 4 + 255) / 256) * 256;
    const size_t pre_bytes = (size_t)NB * NT * HID * sizeof(float);  // 64 MiB
    if (ws_size >= w_pad + pre_bytes) {
        float* Wp = (float*)d_ws;
        float* pre1 = (float*)((char*)d_ws + w_pad);
        pack_kernel<<<(WP_FLOATS + 255) / 256, 256, 0, stream>>>(W1, b1, Wp);
        presig8_kernel<<<NB, 256, 0, stream>>>(features, Wp, pre1);
        scan_kernel<<<NB, 64, 0, stream>>>(pre1, W1, W2, b2, W3, b3, out);
    } else {
        logsig_hedge_fallback<<<NB, 256, 0, stream>>>(features, W1, b1, W2, b2, W3, b3, out);
    }
}

// Round 14
// 282.596 us; speedup vs baseline: 2.1371x; 2.1371x over previous
//
#include <hip/hip_runtime.h>

#define NB 1024
#define NT 256
#define IND 10
#define HID 64

#define KSTEPS 14              // K = 448 (14 x 32)
#define XS 456                 // X row stride in halves (456/8=57 odd -> conflict-free b128)
#define WMF_HALVES (KSTEPS * 4 * 64 * 8)   // 28672 halves = 57344 B

typedef short bf16x8 __attribute__((ext_vector_type(8)));
typedef float f32x4 __attribute__((ext_vector_type(4)));

__device__ __forceinline__ int qmap(int kk) {
    if (kk < 10) return 1 + kk;
    if (kk < 20) return 11 * (kk - 10 + 1);
    int i = (kk - 20) / 10, c = (kk - 20) % 10;
    return 11 * (i + 1) + 1 + c;
}

__device__ __forceinline__ unsigned bf16rne(float x) {
    unsigned u = __float_as_uint(x);
    return (u + 0x7fffu + ((u >> 16) & 1u)) >> 16;
}
__device__ __forceinline__ unsigned pk2(float a, float b) {
    return bf16rne(a) | (bf16rne(b) << 16);
}

// X column semantics (K=448):
//  [0,128):   P (wave slice w at 32w+i, i<30; scaled by inv_k for comps<20)
//  [128,256): rel0 * P
//  [256,384): rel1 * P
//  [384,400): rel2 * Pd (Pd = P[0..9], P[10], P[20..24])
//  [400,410): rel ; [410,420): F ; [420,424): ttv, ttv*rel0, ttv*rel1, ttv*rel2
//  [424]: gate ; [425]: 1.0 (bias) ; rest 0
__device__ float wm_value(int kk, int j, const float* __restrict__ W1,
                          const float* __restrict__ b1) {
    if (kk < 384) {
        int sec = kk >> 7;
        int rem = kk & 127;
        int w = rem >> 5, i = rem & 31;
        if (i >= 30) return 0.f;
        int q = qmap(30 * w + i);
        if (sec == 0) return W1[(11 + q) * 64 + j] + W1[(132 + q) * 64 + j];
        if (sec == 1) return W1[(253 + q) * 64 + j];
        return W1[(374 + q) * 64 + j];
    }
    if (kk < 400) {
        int i = kk - 384;
        if (i < 10) return W1[(496 + i) * 64 + j];
        if (i == 10) return W1[506 * 64 + j];
        return W1[(507 + (i - 11)) * 64 + j];
    }
    if (kk < 410) return W1[(1 + (kk - 400)) * 64 + j];
    if (kk < 420) return W1[(512 + (kk - 410)) * 64 + j];
    if (kk == 420) return W1[11 * 64 + j] + W1[132 * 64 + j];
    if (kk == 421) return W1[253 * 64 + j];
    if (kk == 422) return W1[374 * 64 + j];
    if (kk == 423) return W1[495 * 64 + j];
    if (kk == 424) return W1[0 * 64 + j];
    if (kk == 425) return b1[j];
    return 0.f;
}

// Wmf in exact B-fragment order: record (s, jb) is 64 lanes x 8 halves:
// lane (n = lane&15, quad = lane>>4) holds Wm[32s + quad*8 + idx][16jb + n].
__global__ void pack_mfma_kernel(const float* __restrict__ W1,
                                 const float* __restrict__ b1,
                                 unsigned short* __restrict__ Wmf) {
    int idx = blockIdx.x * 256 + threadIdx.x;
    if (idx >= WMF_HALVES) return;
    int half = idx & 7;
    int lane = (idx >> 3) & 63;
    int rec = idx >> 9;           // s*4 + jb
    int s = rec >> 2, jb = rec & 3;
    int kk = 32 * s + (lane >> 4) * 8 + half;
    int j = 16 * jb + (lane & 15);
    Wmf[idx] = (unsigned short)bf16rne(wm_value(kk, j, W1, b1));
}

// ---------------------------------------------------------------------------
// presig v9: scan phase unchanged (proven spill-free); j-phase replaced by
// MFMA GEMM pre[64t][64j] = X[64t][448] . Wm[448][64j] in bf16 (r13: bf16 P
// costs absmax ~1.0, budget 3.7).  A-frags from LDS (conflict-free b128 via
// XS=456 swizzle); B-frags from global in pre-packed fragment order (L2-hot).
// Layouts per verified m89/m120 maps: A[m=lane&15][k=quad*8+i], B mirrored,
// D col=lane&15 row=quad*4+reg.
// ---------------------------------------------------------------------------
__global__ __launch_bounds__(256, 1) void presig9_kernel(
    const float* __restrict__ features, const unsigned short* __restrict__ Wmf,
    float* __restrict__ pre1) {
    const int b = blockIdx.x;
    const int tid = threadIdx.x;
    const int l = tid & 63;
    const int wu = tid >> 6;

    __shared__ __align__(16) float sF[NT * IND];            // 10240 B
    __shared__ __align__(16) unsigned short sX[64 * XS];    // 58368 B
    __shared__ float sBase[128];                            // 512 B

    {
        const float4* src = (const float4*)(features + b * (NT * IND));
        float4* dst = (float4*)sF;
        for (int e = tid; e < NT * IND / 4; e += 256) dst[e] = src[e];
    }
    float f0[IND];
#pragma unroll
    for (int c = 0; c < IND; ++c) f0[c] = features[b * (NT * IND) + c];

    if (tid < 128) sBase[tid] = 0.f;
    __syncthreads();   // B0: sF + sBase ready

    for (int tile = 0; tile < 4; ++tile) {
        const int t0 = tile * 64;

        // ---- scan phase (identical math to presig7, proven) ----
        const int r = t0 + l;
        float rf = (float)r;
        float fr[IND], rel[IND], inc[IND];
#pragma unroll
        for (int c = 0; c < IND; ++c) fr[c] = sF[r * IND + c];
#pragma unroll
        for (int c = 0; c < IND; ++c) rel[c] = fr[c] - f0[c];
        {
            bool last = (r >= NT - 1);
#pragma unroll
            for (int c = 0; c < IND; ++c)
                inc[c] = last ? 0.f : (sF[(r + 1) * IND + c] - fr[c]);
        }
        float p[30], own[30];
        if (wu == 0) {
#pragma unroll
            for (int c = 0; c < 10; ++c) p[c] = rf * inc[c];
#pragma unroll
            for (int i = 0; i < 10; ++i) p[10 + i] = rel[i];
#pragma unroll
            for (int c = 0; c < 10; ++c) p[20 + c] = rel[0] * inc[c];
        } else {
            const int i0 = 3 * wu - 2;
#pragma unroll
            for (int q = 0; q < 30; ++q) {
                int i = i0 + q / 10, c = q % 10;
                p[q] = rel[i] * inc[c];
            }
        }
#pragma unroll
        for (int i = 0; i < 30; ++i) own[i] = p[i];
#pragma unroll
        for (int dsh = 0; dsh < 6; ++dsh) {
            const int d = 1 << dsh;
            bool ok = (l >= d);
#pragma unroll
            for (int i = 0; i < 30; ++i) {
                float v = __shfl_up(p[i], d, 64);
                if (ok) p[i] += v;
            }
        }
        float inv_r = (r > 0) ? 1.f / rf : 0.f;
        float v[30];
#pragma unroll
        for (int i = 0; i < 30; ++i) {
            float x = sBase[wu * 32 + i] + p[i] - own[i];
            if (wu == 0 && i < 20) x *= inv_r;
            v[i] = x;
        }

        // ---- build X (bf16), immediate uint4 stores (no big live arrays) ----
        {
            float g0 = rel[0], g1 = rel[1];
            uint4* xr = (uint4*)&sX[l * XS];           // raw P at halves 32*wu
            uint4* x0 = (uint4*)&sX[l * XS + 128];     // rel0*P
            uint4* x1 = (uint4*)&sX[l * XS + 256];     // rel1*P
            int qb = 8 * wu;   // uint4 index offset of this wave's 32-half slice is 32*wu halves = 4 uint4
#pragma unroll
            for (int q = 0; q < 3; ++q) {
                uint4 tr, t0v, t1v;
                tr.x = pk2(v[8*q+0], v[8*q+1]); tr.y = pk2(v[8*q+2], v[8*q+3]);
                tr.z = pk2(v[8*q+4], v[8*q+5]); tr.w = pk2(v[8*q+6], v[8*q+7]);
                t0v.x = pk2(g0*v[8*q+0], g0*v[8*q+1]); t0v.y = pk2(g0*v[8*q+2], g0*v[8*q+3]);
                t0v.z = pk2(g0*v[8*q+4], g0*v[8*q+5]); t0v.w = pk2(g0*v[8*q+6], g0*v[8*q+7]);
                t1v.x = pk2(g1*v[8*q+0], g1*v[8*q+1]); t1v.y = pk2(g1*v[8*q+2], g1*v[8*q+3]);
                t1v.z = pk2(g1*v[8*q+4], g1*v[8*q+5]); t1v.w = pk2(g1*v[8*q+6], g1*v[8*q+7]);
                xr[wu * 4 + q] = tr; x0[wu * 4 + q] = t0v; x1[wu * 4 + q] = t1v;
            }
            {   // tail: v[24..29] + 2 zero halves
                uint4 tr, t0v, t1v;
                tr.x = pk2(v[24], v[25]); tr.y = pk2(v[26], v[27]);
                tr.z = pk2(v[28], v[29]); tr.w = 0u;
                t0v.x = pk2(g0*v[24], g0*v[25]); t0v.y = pk2(g0*v[26], g0*v[27]);
                t0v.z = pk2(g0*v[28], g0*v[29]); t0v.w = 0u;
                t1v.x = pk2(g1*v[24], g1*v[25]); t1v.y = pk2(g1*v[26], g1*v[27]);
                t1v.z = pk2(g1*v[28], g1*v[29]); t1v.w = 0u;
                xr[wu * 4 + 3] = tr; x0[wu * 4 + 3] = t0v; x1[wu * 4 + 3] = t1v;
            }
            (void)qb;
        }
        if (wu == 0) {   // extras: halves [384,456) of row l
            float g2 = rel[2];
            float ttv = 0.5f * (rf - 1.f) * inv_r;
            float gate = (r > 0) ? 1.f : 0.f;
            uint4* xe = (uint4*)&sX[l * XS + 384];
            uint4 u;
            u.x = pk2(g2*v[0], g2*v[1]);  u.y = pk2(g2*v[2], g2*v[3]);
            u.z = pk2(g2*v[4], g2*v[5]);  u.w = pk2(g2*v[6], g2*v[7]);
            xe[0] = u;
            u.x = pk2(g2*v[8], g2*v[9]);  u.y = pk2(g2*v[10], g2*v[20]);
            u.z = pk2(g2*v[21], g2*v[22]); u.w = pk2(g2*v[23], g2*v[24]);
            xe[1] = u;
            u.x = pk2(rel[0], rel[1]); u.y = pk2(rel[2], rel[3]);
            u.z = pk2(rel[4], rel[5]); u.w = pk2(rel[6], rel[7]);
            xe[2] = u;
            u.x = pk2(rel[8], rel[9]); u.y = pk2(fr[0], fr[1]);
            u.z = pk2(fr[2], fr[3]);   u.w = pk2(fr[4], fr[5]);
            xe[3] = u;
            u.x = pk2(fr[6], fr[7]); u.y = pk2(fr[8], fr[9]);
            u.z = pk2(ttv, ttv * rel[0]); u.w = pk2(ttv * rel[1], ttv * rel[2]);
            xe[4] = u;
            u.x = pk2(gate, 1.0f); u.y = 0u; u.z = 0u; u.w = 0u;
            xe[5] = u;
            u.x = 0u; u.y = 0u; u.z = 0u; u.w = 0u;
            xe[6] = u; xe[7] = u;
            // halves 448..455 (stride pad) — never read (X cols < 448), skip
        }
        if (l == 63) {
#pragma unroll
            for (int i = 0; i < 30; ++i) sBase[wu * 32 + i] += p[i];
        }
        __syncthreads();   // Bx: X complete (cross-wave reads next)

        // ---- MFMA j-phase: wave wu computes t-rows [16wu,16wu+16) x all j ----
        {
            const int m = l & 15, quad = l >> 4;
            const unsigned short* arow = &sX[(16 * wu + m) * XS + 8 * quad];
            const bf16x8* bp = (const bf16x8*)Wmf;
            f32x4 ac0 = {0.f, 0.f, 0.f, 0.f}, ac1 = ac0, ac2 = ac0, ac3 = ac0;
#pragma unroll
            for (int s = 0; s < KSTEPS; ++s) {
                bf16x8 af = *(const bf16x8*)(arow + 32 * s);
                bf16x8 bf0 = bp[(s * 4 + 0) * 64 + l];
                bf16x8 bf1 = bp[(s * 4 + 1) * 64 + l];
                bf16x8 bf2 = bp[(s * 4 + 2) * 64 + l];
                bf16x8 bf3 = bp[(s * 4 + 3) * 64 + l];
                ac0 = __builtin_amdgcn_mfma_f32_16x16x32_bf16(af, bf0, ac0, 0, 0, 0);
                ac1 = __builtin_amdgcn_mfma_f32_16x16x32_bf16(af, bf1, ac1, 0, 0, 0);
                ac2 = __builtin_amdgcn_mfma_f32_16x16x32_bf16(af, bf2, ac2, 0, 0, 0);
                ac3 = __builtin_amdgcn_mfma_f32_16x16x32_bf16(af, bf3, ac3, 0, 0, 0);
            }
            float* op = pre1 + b * (NT * HID) + (t0 + 16 * wu) * HID + m;
            const int rowb = quad * 4;
#pragma unroll
            for (int reg = 0; reg < 4; ++reg) {
                op[(rowb + reg) * HID + 0]  = ac0[reg];
                op[(rowb + reg) * HID + 16] = ac1[reg];
                op[(rowb + reg) * HID + 32] = ac2[reg];
                op[(rowb + reg) * HID + 48] = ac3[reg];
            }
        }
        __syncthreads();   // Be: all X reads done before next tile rewrites
    }
}

// ---------------------------------------------------------------------------
// scan (r9/r12-proven, ~120 us): 1 wave per batch, grid 1024.  LDS-b128
// broadcast GEMV, NO barriers (single-wave lgkmcnt ordering), DPP reduce,
// 8-deep global prefetch ring.
// ---------------------------------------------------------------------------
template <int CTRL, int RMASK>
__device__ __forceinline__ float dpp_add(float x) {
    int v = __builtin_amdgcn_update_dpp(0, __float_as_int(x), CTRL, RMASK, 0xf, false);
    return x + __int_as_float(v);
}

#define W2_EACH(X) X(0) X(1) X(2) X(3) X(4) X(5) X(6) X(7) \
    X(8) X(9) X(10) X(11) X(12) X(13) X(14) X(15)

__global__ __launch_bounds__(64, 1) void scan_kernel(
    const float* __restrict__ pre1, const float* __restrict__ W1,
    const float* __restrict__ W2, const float* __restrict__ b2,
    const float* __restrict__ W3, const float* __restrict__ b3,
    float* __restrict__ out) {
    const int b = blockIdx.x;
    const int j = threadIdx.x;

    __shared__ __align__(16) float sH[64];

#define DECLW(q) float4 w2_##q = make_float4( \
        W2[(4*(q)+0)*64 + j], W2[(4*(q)+1)*64 + j], \
        W2[(4*(q)+2)*64 + j], W2[(4*(q)+3)*64 + j]);
    W2_EACH(DECLW)
#undef DECLW
    float w1l = W1[522 * 64 + j];
    float b2j = b2[j], w3j = W3[j], b3v = b3[0];

    const float* pb_ = pre1 + b * (NT * HID);
    float delta = 0.f;
    float outbuf = 0.f;

#define GEMVQ(q) { float4 h4 = *(const float4*)&sH[4*(q)]; \
        a0 = fmaf(h4.x, w2_##q.x, a0); a1 = fmaf(h4.y, w2_##q.y, a1); \
        a2 = fmaf(h4.z, w2_##q.z, a2); a3 = fmaf(h4.w, w2_##q.w, a3); }

#define SCAN_STEP(pv, mm) { \
        float h1 = fmaxf(fmaf(delta, w1l, (pv)), 0.f); \
        sH[j] = h1; \
        float a0 = 0.f, a1 = 0.f, a2 = 0.f, a3 = 0.f; \
        W2_EACH(GEMVQ) \
        float h2 = fmaxf((a0 + a1) + (a2 + a3) + b2j, 0.f); \
        float qv = h2 * w3j; \
        qv = dpp_add<0x111, 0xf>(qv); \
        qv = dpp_add<0x112, 0xf>(qv); \
        qv = dpp_add<0x114, 0xf>(qv); \
        qv = dpp_add<0x118, 0xf>(qv); \
        qv = dpp_add<0x142, 0xa>(qv); \
        qv = dpp_add<0x143, 0xc>(qv); \
        float tot = __uint_as_float(__builtin_amdgcn_readlane(__float_as_uint(qv), 63)); \
        delta = tot + b3v; \
        if (j == ((mm) & 63)) outbuf = delta; \
        if (((mm) & 63) == 63) out[b * NT + ((mm) & ~63) + j] = outbuf; }

    float r0 = pb_[0 * 64 + j], r1 = pb_[1 * 64 + j], r2 = pb_[2 * 64 + j],
          r3 = pb_[3 * 64 + j], r4 = pb_[4 * 64 + j], r5 = pb_[5 * 64 + j],
          r6 = pb_[6 * 64 + j], r7 = pb_[7 * 64 + j];
    for (int g = 0; g < NT; g += 8) {
        int nb = g + 8;
        float n0 = pb_[min(nb + 0, NT - 1) * 64 + j];
        float n1 = pb_[min(nb + 1, NT - 1) * 64 + j];
        float n2 = pb_[min(nb + 2, NT - 1) * 64 + j];
        float n3 = pb_[min(nb + 3, NT - 1) * 64 + j];
        float n4 = pb_[min(nb + 4, NT - 1) * 64 + j];
        float n5 = pb_[min(nb + 5, NT - 1) * 64 + j];
        float n6 = pb_[min(nb + 6, NT - 1) * 64 + j];
        float n7 = pb_[min(nb + 7, NT - 1) * 64 + j];
        SCAN_STEP(r0, g + 0)
        SCAN_STEP(r1, g + 1)
        SCAN_STEP(r2, g + 2)
        SCAN_STEP(r3, g + 3)
        SCAN_STEP(r4, g + 4)
        SCAN_STEP(r5, g + 5)
        SCAN_STEP(r6, g + 6)
        SCAN_STEP(r7, g + 7)
        r0 = n0; r1 = n1; r2 = n2; r3 = n3; r4 = n4; r5 = n5; r6 = n6; r7 = n7;
    }
#undef SCAN_STEP
#undef GEMVQ
}

// ---------------------------------------------------------------------------
// Fallback (round-1 fused kernel) if workspace is too small.
// ---------------------------------------------------------------------------
__global__ __launch_bounds__(256) void logsig_hedge_fallback(
    const float* __restrict__ features, const float* __restrict__ W1,
    const float* __restrict__ b1, const float* __restrict__ W2,
    const float* __restrict__ b2, const float* __restrict__ W3,
    const float* __restrict__ b3, float* __restrict__ out) {
    const int b = blockIdx.x;
    const int tid = threadIdx.x;
    const int j = tid & 63;
    const int s = tid >> 6;

    __shared__ __align__(16) float sF[NT * IND];
    __shared__ __align__(16) float sSig[128];
    __shared__ float sA[IND], sB[IND], sC[IND * IND];
    __shared__ float sRel[IND];
    __shared__ __align__(16) float sPart[4 * 64];
    __shared__ __align__(16) float sH1[64];

    for (int idx = tid; idx < NT * IND; idx += 256)
        sF[idx] = features[b * (NT * IND) + idx];
    if (tid < 100) sC[tid] = 0.f;
    else if (tid < 110) sA[tid - 100] = 0.f;
    else if (tid < 120) sB[tid - 110] = 0.f;
    else if (tid >= 121 && tid < 128) sSig[tid] = 0.f;

    float vs[32], vb[32], vc[32];
#pragma unroll
    for (int mm = 0; mm < 32; ++mm) {
        int mp = 32 * s + mm;
        if (mp < 121) {
            vs[mm] = W1[(11 + mp) * 64 + j] + W1[(132 + mp) * 64 + j];
            vb[mm] = W1[(253 + mp) * 64 + j];
            vc[mm] = W1[(374 + mp) * 64 + j];
        } else { vs[mm] = 0.f; vb[mm] = 0.f; vc[mm] = 0.f; }
    }
    float ex[17];
#pragma unroll
    for (int q = 0; q < 17; ++q) ex[q] = 0.f;
    if (s == 1) {
#pragma unroll
        for (int q = 0; q < 11; ++q) ex[q] = W1[q * 64 + j];
    } else if (s == 2) {
#pragma unroll
        for (int q = 0; q < 10; ++q) ex[q] = W1[(512 + q) * 64 + j];
        ex[10] = b1[j];
    } else if (s == 3) {
#pragma unroll
        for (int q = 0; q < 17; ++q) ex[q] = W1[(495 + q) * 64 + j];
    }
    float w2p[16];
#pragma unroll
    for (int ii = 0; ii < 16; ++ii) w2p[ii] = W2[(16 * s + ii) * 64 + j];

    float w1l = 0.f, b2j = 0.f, w3j = 0.f, b3v = 0.f;
    if (s == 0) { w1l = W1[522 * 64 + j]; b2j = b2[j]; w3j = W3[j]; b3v = b3[0]; }
    float delta = 0.f;

    __syncthreads();

    for (int m = 0; m < NT; ++m) {
        if (m > 0) {
            if (tid < 100) {
                int i = tid / 10, c = tid % 10;
                float rp = sF[(m - 1) * 10 + i] - sF[i];
                float ic = sF[m * 10 + c] - sF[(m - 1) * 10 + c];
                sC[tid] += rp * ic;
            } else if (tid < 110) {
                int i = tid - 100;
                sA[i] += (float)(m - 1) * (sF[m * 10 + i] - sF[(m - 1) * 10 + i]);
            } else if (tid < 120) {
                int i = tid - 110;
                sB[i] += sF[(m - 1) * 10 + i] - sF[i];
            }
            __syncthreads();
            float inv_k = 1.0f / (float)m;
            if (tid == 0) sSig[0] = 0.5f * (float)(m - 1) * inv_k;
            else if (tid < 11) sSig[tid] = inv_k * sA[tid - 1];
            else if (tid < 121) {
                int i = tid / 11 - 1, c = tid % 11;
                sSig[tid] = (c == 0) ? inv_k * sB[i] : sC[i * 10 + (c - 1)];
            } else if (tid < 131) {
                int f = tid - 121;
                sRel[f] = sF[m * 10 + f] - sF[f];
            }
            __syncthreads();
        }
        float part = 0.f;
        if (m > 0) {
            float pa = 0.f, pb = 0.f, pc = 0.f;
#pragma unroll
            for (int q = 0; q < 8; ++q) {
                float4 sv = *(const float4*)&sSig[32 * s + 4 * q];
                pa = fmaf(sv.x, vs[4 * q + 0], pa);
                pb = fmaf(sv.x, vb[4 * q + 0], pb);
                pc = fmaf(sv.x, vc[4 * q + 0], pc);
                pa = fmaf(sv.y, vs[4 * q + 1], pa);
                pb = fmaf(sv.y, vb[4 * q + 1], pb);
                pc = fmaf(sv.y, vc[4 * q + 1], pc);
                pa = fmaf(sv.z, vs[4 * q + 2], pa);
                pb = fmaf(sv.z, vb[4 * q + 2], pb);
                pc = fmaf(sv.z, vc[4 * q + 2], pc);
                pa = fmaf(sv.w, vs[4 * q + 3], pa);
                pb = fmaf(sv.w, vb[4 * q + 3], pb);
                pc = fmaf(sv.w, vc[4 * q + 3], pc);
            }
            part = pa + sRel[0] * pb + sRel[1] * pc;
            if (s == 3) {
                float pd = 0.f;
#pragma unroll
                for (int q = 0; q < 17; ++q) pd = fmaf(sSig[q], ex[q], pd);
                part = fmaf(sRel[2], pd, part);
            }
            if (s == 1) {
                part += ex[0];
#pragma unroll
                for (int i = 0; i < 10; ++i) part = fmaf(sRel[i], ex[1 + i], part);
            }
        }
        if (s == 2) {
            float pf = ex[10];
#pragma unroll
            for (int f = 0; f < 10; ++f) pf = fmaf(sF[m * 10 + f], ex[f], pf);
            part += pf;
        }
        sPart[s * 64 + j] = part;
        __syncthreads();
        if (s == 0) {
            float x = sPart[j] + sPart[64 + j] + sPart[128 + j] + sPart[192 + j];
            sH1[j] = fmaxf(fmaf(delta, w1l, x), 0.f);
        }
        __syncthreads();
        {
            float hp = 0.f;
#pragma unroll
            for (int q = 0; q < 4; ++q) {
                float4 hv = *(const float4*)&sH1[16 * s + 4 * q];
                hp = fmaf(hv.x, w2p[4 * q + 0], hp);
                hp = fmaf(hv.y, w2p[4 * q + 1], hp);
                hp = fmaf(hv.z, w2p[4 * q + 2], hp);
                hp = fmaf(hv.w, w2p[4 * q + 3], hp);
            }
            sPart[s * 64 + j] = hp;
        }
        __syncthreads();
        if (s == 0) {
            float x2 = sPart[j] + sPart[64 + j] + sPart[128 + j] + sPart[192 + j] + b2j;
            float h2 = fmaxf(x2, 0.f);
            float dv = h2 * w3j;
#pragma unroll
            for (int off = 32; off > 0; off >>= 1) dv += __shfl_xor(dv, off, 64);
            delta = dv + b3v;
            if (j == 0) out[b * NT + m] = delta;
        }
        __syncthreads();
    }
}

extern "C" void kernel_launch(void* const* d_in, const int* in_sizes, int n_in,
                              void* d_out, int out_size, void* d_ws, size_t ws_size,
                              hipStream_t stream) {
    const float* features = (const float*)d_in[0];
    const float* W1 = (const float*)d_in[1];
    const float* b1 = (const float*)d_in[2];
    const float* W2 = (const float*)d_in[3];
    const float* b2 = (const float*)d_in[4];
    const float* W3 = (const float*)d_in[5];
    const float* b3 = (const float*)d_in[6];
    float* out = (float*)d_out;

    const size_t wmf_bytes = (size_t)WMF_HALVES * 2;                 // 57344
    const size_t w_pad     = ((wmf_bytes + 255) / 256) * 256;
    const size_t pre_bytes = (size_t)NB * NT * HID * sizeof(float);  // 64 MiB
    if (ws_size >= w_pad + pre_bytes) {
        unsigned short* Wmf = (unsigned short*)d_ws;
        float* pre1 = (float*)((char*)d_ws + w_pad);
        pack_mfma_kernel<<<(WMF_HALVES + 255) / 256, 256, 0, stream>>>(W1, b1, Wmf);
        presig9_kernel<<<NB, 256, 0, stream>>>(features, Wmf, pre1);
        scan_kernel<<<NB, 64, 0, stream>>>(pre1, W1, W2, b2, W3, b3, out);
    } else {
        logsig_hedge_fallback<<<NB, 256, 0, stream>>>(features, W1, b1, W2, b2, W3, b3, out);
    }
}